// Round 6
// baseline (648.427 us; speedup 1.0000x reference)
//
#include <hip/hip_runtime.h>
#include <math.h>

#define N_NODES 100000
#define N_EDGES 1600000
#define F_IN    512
#define HD1     64    // 8 heads x 8 dims
#define NHEAD   8
#define NC      40
#define NEG_SLOPE 0.2f

typedef _Float16 h8 __attribute__((ext_vector_type(8)));
typedef float f4 __attribute__((ext_vector_type(4)));

// ------------- fused weight prep (btg1 frag-major, btg2 plain) + deg zero ---
__global__ __launch_bounds__(256) void conv_w(
    const float* __restrict__ W1s, const float* __restrict__ W1d,
    const float* __restrict__ W2s, const float* __restrict__ W2d,
    _Float16* __restrict__ btg1, _Float16* __restrict__ btg2,
    int* __restrict__ deg){
  int i = blockIdx.x*256 + threadIdx.x;
  if(i < 65536){
    // frag (kstep 0..15, t 0..7): elem[lane][j] = W[kstep*32+(lane>>4)*8+j][t*16+(lane&15)]
    int j = i & 7, lane = (i>>3)&63, t = (i>>9)&7, kstep = i>>12;
    int k = kstep*32 + (lane>>4)*8 + j;
    int n = t*16 + (lane&15);
    float v = (n < 64) ? W1s[k*64 + n] : W1d[k*64 + (n-64)];
    btg1[i] = (_Float16)v;
  } else if(i < 65536 + 80*64){
    int idx = i - 65536;
    int n = idx >> 6, k = idx & 63;
    float v = (n < 40) ? W2s[k*40 + n] : W2d[k*40 + (n-40)];
    btg2[idx] = (_Float16)v;
  }
  if(i < N_NODES) deg[i] = 0;
}

// ---------------------------------------------------------------- CSR build
// XCD-sharded histogram: block b -> shard b&7 owns dst range [shard*12500,+12500)
__global__ __launch_bounds__(256) void hist_dst(const int* __restrict__ dst,
                                                int* __restrict__ deg){
  int xcd = blockIdx.x & 7;
  int lo = xcd*12500, hi = lo + 12500;
  int e = (blockIdx.x >> 3)*1024 + threadIdx.x;
  #pragma unroll
  for(int j=0;j<4;j++, e+=256){
    if(e < N_EDGES){
      int d = dst[e];
      if(d >= lo && d < hi) atomicAdd(&deg[d], 1);
    }
  }
}

__global__ __launch_bounds__(256) void scan1(const int* __restrict__ deg,
                                             int* __restrict__ row,
                                             int* __restrict__ bsum){
  __shared__ int sm[256];
  int t = threadIdx.x;
  int base = blockIdx.x*1024 + t*4;
  int v0 = base+0<N_NODES ? deg[base+0] : 0;
  int v1 = base+1<N_NODES ? deg[base+1] : 0;
  int v2 = base+2<N_NODES ? deg[base+2] : 0;
  int v3 = base+3<N_NODES ? deg[base+3] : 0;
  int tsum = v0+v1+v2+v3;
  sm[t] = tsum; __syncthreads();
  for(int off=1; off<256; off<<=1){
    int x = (t>=off) ? sm[t-off] : 0;
    __syncthreads();
    sm[t] += x;
    __syncthreads();
  }
  int excl = sm[t] - tsum;
  if(t==255) bsum[blockIdx.x] = sm[255];
  if(base+0<N_NODES) row[base+0] = excl;
  if(base+1<N_NODES) row[base+1] = excl+v0;
  if(base+2<N_NODES) row[base+2] = excl+v0+v1;
  if(base+3<N_NODES) row[base+3] = excl+v0+v1+v2;
}

__global__ __launch_bounds__(128) void scan2(int* __restrict__ bsum, int nb){
  __shared__ int sm[128];
  int t = threadIdx.x;
  int v = (t<nb) ? bsum[t] : 0;
  sm[t] = v; __syncthreads();
  for(int off=1; off<128; off<<=1){
    int x = (t>=off) ? sm[t-off] : 0;
    __syncthreads();
    sm[t] += x;
    __syncthreads();
  }
  if(t<nb) bsum[t] = sm[t] - v;   // exclusive block offsets
}

__global__ __launch_bounds__(256) void scan3(int* __restrict__ row,
                                             const int* __restrict__ bsum,
                                             int* __restrict__ cur){
  int i = blockIdx.x*256 + threadIdx.x;
  if(i >= N_NODES) return;
  int r = row[i] + bsum[i>>10];
  row[i] = r; cur[i] = r;
}

// XCD-sharded scatter; src read unconditionally (coalesced) before the filter.
__global__ __launch_bounds__(256) void scatter_edges(const int* __restrict__ src,
                                                     const int* __restrict__ dst,
                                                     int* __restrict__ cur,
                                                     int* __restrict__ esrc){
  int xcd = blockIdx.x & 7;
  int lo = xcd*12500, hi = lo + 12500;
  int e = (blockIdx.x >> 3)*1024 + threadIdx.x;
  #pragma unroll
  for(int j=0;j<4;j++, e+=256){
    if(e < N_EDGES){
      int d = dst[e];
      int sv = src[e];                 // coalesced, unconditional
      if(d >= lo && d < hi){
        int pos = atomicAdd(&cur[d], 1);
        esrc[pos] = sv;
      }
    }
  }
}

// ---------------- layer-1 GEMM: LDS-free streaming fp16 MFMA ----------------
// wave = 16 rows x 128 cols; block = 4 waves = 64 rows. A direct from global
// (2x float4/lane/kstep, coalesced: 4 quads cover each row's 128B), B from
// the pre-swizzled 128KB frag table (L2-hot). No barriers, no LDS.
__global__ __launch_bounds__(256) void gemm1_mfma(
    const float* __restrict__ x, const _Float16* __restrict__ btgf,
    const float* __restrict__ bs, const float* __restrict__ bd,
    _Float16* __restrict__ hs, _Float16* __restrict__ hd){
  int tid = threadIdx.x;
  int lane = tid & 63, w = tid >> 6;
  int l15 = lane & 15, quad = lane >> 4;
  int row0 = blockIdx.x*64 + w*16;
  int r = row0 + l15; if(r >= N_NODES) r = N_NODES-1;
  const float* ap = x + (long)r*F_IN + quad*8;

  f4 acc[8];
  #pragma unroll
  for(int t=0;t<8;t++) acc[t] = (f4){0.f,0.f,0.f,0.f};

  #pragma unroll 2
  for(int ks=0; ks<16; ks++){
    float4 q0 = *(const float4*)(ap + ks*32);
    float4 q1 = *(const float4*)(ap + ks*32 + 4);
    h8 af;
    af[0]=(_Float16)q0.x; af[1]=(_Float16)q0.y; af[2]=(_Float16)q0.z; af[3]=(_Float16)q0.w;
    af[4]=(_Float16)q1.x; af[5]=(_Float16)q1.y; af[6]=(_Float16)q1.z; af[7]=(_Float16)q1.w;
    const _Float16* fb = btgf + ks*4096 + lane*8;
    #pragma unroll
    for(int t=0;t<8;t++){
      h8 bf = *(const h8*)(fb + t*512);
      acc[t] = __builtin_amdgcn_mfma_f32_16x16x32_f16(af, bf, acc[t], 0,0,0);
    }
  }
  // epilogue: C/D map col=lane&15, row=quad*4+reg
  #pragma unroll
  for(int t=0;t<8;t++){
    int colg = t*16 + l15;
    float bv; _Float16* op; int c;
    if(colg < 64){ bv = bs[colg]; op = hs; c = colg; }
    else         { bv = bd[colg-64]; op = hd; c = colg-64; }
    #pragma unroll
    for(int reg=0;reg<4;reg++){
      int rr = row0 + quad*4 + reg;
      if(rr < N_NODES) op[rr*HD1 + c] = (_Float16)(acc[t][reg] + bv);
    }
  }
}

// ---------------- layer-2 GEMM via fp16 MFMA (B in registers, fp16 out) -----
__global__ __launch_bounds__(256) void gemm2_mfma(
    const _Float16* __restrict__ h1h, const _Float16* __restrict__ btg,
    const float* __restrict__ bs, const float* __restrict__ bd,
    _Float16* __restrict__ hs2, _Float16* __restrict__ hd2){
  int tid = threadIdx.x;
  int lane = tid & 63, w = tid >> 6;
  int l15 = lane & 15, quad = lane >> 4;
  int rbase = blockIdx.x*192 + w*48;
  h8 bf[2][5];
  #pragma unroll
  for(int ks=0;ks<2;ks++)
    #pragma unroll
    for(int t=0;t<5;t++)
      bf[ks][t] = *(const h8*)&btg[(t*16 + l15)*64 + ks*32 + quad*8];
  f4 acc[3][5];
  #pragma unroll
  for(int mt=0;mt<3;mt++)
    #pragma unroll
    for(int t=0;t<5;t++) acc[mt][t] = (f4){0.f,0.f,0.f,0.f};
  #pragma unroll
  for(int mt=0;mt<3;mt++){
    int r = rbase + mt*16 + l15;
    if(r >= N_NODES) r = N_NODES-1;
    const _Float16* ap = h1h + r*HD1 + quad*8;
    #pragma unroll
    for(int ks=0;ks<2;ks++){
      h8 af = *(const h8*)(ap + ks*32);
      #pragma unroll
      for(int t=0;t<5;t++)
        acc[mt][t] = __builtin_amdgcn_mfma_f32_16x16x32_f16(af, bf[ks][t], acc[mt][t], 0,0,0);
    }
  }
  #pragma unroll
  for(int t=0;t<5;t++){
    int colg = t*16 + l15;
    float bv; _Float16* op; int c;
    if(colg < 40){ bv = bs[colg]; op = hs2; c = colg; }
    else         { bv = bd[colg-40]; op = hd2; c = colg-40; }
    #pragma unroll
    for(int mt=0;mt<3;mt++)
      #pragma unroll
      for(int reg=0;reg<4;reg++){
        int rr = rbase + mt*16 + quad*4 + reg;
        if(rr < N_NODES) op[rr*NC + c] = (_Float16)(acc[mt][t][reg] + bv);
      }
  }
}

// ---------------- layer-1 fused attention: wave/node, 8 edges/iter ----------
__global__ __launch_bounds__(256) void node_attn1(
    const _Float16* __restrict__ hs, const _Float16* __restrict__ hd,
    const int* __restrict__ row, const int* __restrict__ deg,
    const int* __restrict__ esrc, const float* __restrict__ attn,
    _Float16* __restrict__ out){
  int node = blockIdx.x*4 + (threadIdx.x>>6);
  int lane = threadIdx.x & 63;
  if(node >= N_NODES) return;
  int h  = lane & 7;
  int es = lane >> 3;
  h8 hdh = *(const h8*)&hd[node*HD1 + h*8];
  float4 a0 = *(const float4*)&attn[h*8];
  float4 a1 = *(const float4*)&attn[h*8+4];
  float hdv[8], av[8];
  hdv[0]=(float)hdh[0]; hdv[1]=(float)hdh[1]; hdv[2]=(float)hdh[2]; hdv[3]=(float)hdh[3];
  hdv[4]=(float)hdh[4]; hdv[5]=(float)hdh[5]; hdv[6]=(float)hdh[6]; hdv[7]=(float)hdh[7];
  av[0]=a0.x; av[1]=a0.y; av[2]=a0.z; av[3]=a0.w;
  av[4]=a1.x; av[5]=a1.y; av[6]=a1.z; av[7]=a1.w;
  int st = row[node], en = st + deg[node];
  float m = -1e30f, sum = 0.f;
  float acc[8] = {0.f,0.f,0.f,0.f,0.f,0.f,0.f,0.f};
  for(int base = st; base < en; base += 8){
    int idx = base + es;
    bool val = idx < en;
    int s = esrc[val ? idx : st];
    h8 hsh = *(const h8*)&hs[s*HD1 + h*8];
    float hsv[8]; float t = 0.f;
    #pragma unroll
    for(int j=0;j<8;j++){
      hsv[j] = (float)hsh[j];
      float v = hsv[j] + hdv[j];
      v = fmaxf(v, NEG_SLOPE*v);           // leaky-relu (slope<1)
      t = fmaf(v, av[j], t);
    }
    if(!val) t = -1e30f;
    float tm = t;                           // per-head max across eslots
    tm = fmaxf(tm, __shfl_xor(tm,8));
    tm = fmaxf(tm, __shfl_xor(tm,16));
    tm = fmaxf(tm, __shfl_xor(tm,32));
    float mn = fmaxf(m, tm);
    float eo = __expf(m - mn);
    float p  = __expf(t - mn);              // 0 for invalid slots
    sum = sum*eo + p;
    #pragma unroll
    for(int j=0;j<8;j++) acc[j] = fmaf(p, hsv[j], acc[j]*eo);
    m = mn;
  }
  sum += __shfl_xor(sum,8); sum += __shfl_xor(sum,16); sum += __shfl_xor(sum,32);
  #pragma unroll
  for(int j=0;j<8;j++){
    acc[j] += __shfl_xor(acc[j],8);
    acc[j] += __shfl_xor(acc[j],16);
    acc[j] += __shfl_xor(acc[j],32);
  }
  if(es == 0){
    float inv = 1.f / (sum + 1e-9f);
    h8 o;
    #pragma unroll
    for(int j=0;j<8;j++){
      float r = acc[j] * inv;
      r = r>0.f ? r : expm1f(r);            // ELU fused
      o[j] = (_Float16)r;
    }
    *(h8*)&out[node*HD1 + h*8] = o;
  }
}

// ---------------- layer-2 fused attention: wave/node, 8 edges/iter ----------
// lane = (eslot = lane>>3, f = lane&7); f<5 active, each covers 8 feats via
// one aligned 16B load (row = 80B = 5x16B).
__global__ __launch_bounds__(256) void node_attn2(
    const _Float16* __restrict__ hs, const _Float16* __restrict__ hd,
    const int* __restrict__ row, const int* __restrict__ deg,
    const int* __restrict__ esrc, const float* __restrict__ attn,
    float* __restrict__ out){
  int node = blockIdx.x*4 + (threadIdx.x>>6);
  int lane = threadIdx.x & 63;
  if(node >= N_NODES) return;
  int f  = lane & 7;
  int es = lane >> 3;
  bool act = f < 5;
  float hdv[8], av[8];
  if(act){
    h8 hh = *(const h8*)&hd[node*NC + f*8];
    #pragma unroll
    for(int j=0;j<8;j++){ hdv[j] = (float)hh[j]; av[j] = attn[f*8 + j]; }
  } else {
    #pragma unroll
    for(int j=0;j<8;j++){ hdv[j] = 0.f; av[j] = 0.f; }
  }
  int st = row[node], en = st + deg[node];
  float m = -1e30f, sum = 0.f;
  float acc[8] = {0.f,0.f,0.f,0.f,0.f,0.f,0.f,0.f};
  for(int base = st; base < en; base += 8){
    int idx = base + es;
    bool val = idx < en;
    int s = esrc[val ? idx : st];
    float hsv[8]; float t = 0.f;
    if(act){
      h8 sh = *(const h8*)&hs[s*NC + f*8];
      #pragma unroll
      for(int j=0;j<8;j++){
        hsv[j] = (float)sh[j];
        float v = hsv[j] + hdv[j];
        v = fmaxf(v, NEG_SLOPE*v);
        t = fmaf(v, av[j], t);
      }
    } else {
      #pragma unroll
      for(int j=0;j<8;j++) hsv[j] = 0.f;
    }
    t += __shfl_xor(t,1); t += __shfl_xor(t,2); t += __shfl_xor(t,4);
    if(!val) t = -1e30f;
    float tm = t;
    tm = fmaxf(tm, __shfl_xor(tm,8));
    tm = fmaxf(tm, __shfl_xor(tm,16));
    tm = fmaxf(tm, __shfl_xor(tm,32));
    float mn = fmaxf(m, tm);
    float eo = __expf(m - mn);
    float p  = __expf(t - mn);
    sum = sum*eo + p;
    #pragma unroll
    for(int j=0;j<8;j++) acc[j] = fmaf(p, hsv[j], acc[j]*eo);
    m = mn;
  }
  sum += __shfl_xor(sum,8); sum += __shfl_xor(sum,16); sum += __shfl_xor(sum,32);
  #pragma unroll
  for(int j=0;j<8;j++){
    acc[j] += __shfl_xor(acc[j],8);
    acc[j] += __shfl_xor(acc[j],16);
    acc[j] += __shfl_xor(acc[j],32);
  }
  if(es == 0 && act){
    float inv = 1.f / (sum + 1e-9f);
    float4 o0, o1;
    o0.x=acc[0]*inv; o0.y=acc[1]*inv; o0.z=acc[2]*inv; o0.w=acc[3]*inv;
    o1.x=acc[4]*inv; o1.y=acc[5]*inv; o1.z=acc[6]*inv; o1.w=acc[7]*inv;
    *(float4*)&out[node*NC + f*8]     = o0;
    *(float4*)&out[node*NC + f*8 + 4] = o1;
  }
}

extern "C" void kernel_launch(void* const* d_in, const int* in_sizes, int n_in,
                              void* d_out, int out_size, void* d_ws, size_t ws_size,
                              hipStream_t stream) {
  const float* x   = (const float*)d_in[0];
  const int*   src = (const int*)  d_in[1];
  const int*   dst = (const int*)  d_in[2];
  const float* W1s = (const float*)d_in[3];
  const float* b1s = (const float*)d_in[4];
  const float* W1d = (const float*)d_in[5];
  const float* b1d = (const float*)d_in[6];
  const float* a1  = (const float*)d_in[7];
  const float* W2s = (const float*)d_in[8];
  const float* b2s = (const float*)d_in[9];
  const float* W2d = (const float*)d_in[10];
  const float* b2d = (const float*)d_in[11];
  const float* a2  = (const float*)d_in[12];
  float* out = (float*)d_out;

  // workspace layout (float-offset arithmetic; all 16B-aligned)
  float* ws = (float*)d_ws;
  _Float16* hs1h = (_Float16*)ws;                  // 6.4M halfs (3.2M f)
  _Float16* hd1h = (_Float16*)(ws + 3200000);      // 6.4M halfs
  _Float16* h1h  = (_Float16*)(ws + 6400000);      // 6.4M halfs
  _Float16* hs2h = (_Float16*)(ws + 9600000);      // 4.0M halfs (2M f)
  _Float16* hd2h = (_Float16*)(ws + 11600000);     // 4.0M halfs
  _Float16* btg1 = (_Float16*)(ws + 13600000);     // 65536 halfs (frag-major)
  _Float16* btg2 = (_Float16*)(ws + 13632768);     // 5120 halfs
  int*   deg  = (int*)(ws + 13635328);             // 100k
  int*   row  = deg  + 100000;
  int*   cur  = row  + 100000;
  int*   bsum = cur  + 100000;                     // 128
  int*   esrc = bsum + 128;                        // 1.6M

  dim3 b256(256);
  const int NB = (N_NODES+255)/256;         // 391
  const int SB = (N_NODES+1023)/1024;       // 98 scan blocks
  const int G1 = (N_NODES+63)/64;           // 1563 gemm1 blocks
  const int G2 = (N_NODES+191)/192;         // 521 gemm2 blocks
  const int XB = ((N_EDGES+1023)/1024)*8;   // 12504 sharded-sweep blocks

  // ---- weight prep + deg zero (fused)
  conv_w<<<NB, b256, 0, stream>>>(W1s, W1d, W2s, W2d, btg1, btg2, deg);

  // ---- CSR build (graph identical for both layers)
  hist_dst<<<XB, b256, 0, stream>>>(dst, deg);
  scan1<<<SB, b256, 0, stream>>>(deg, row, bsum);
  scan2<<<1, dim3(128), 0, stream>>>(bsum, SB);
  scan3<<<NB, b256, 0, stream>>>(row, bsum, cur);
  scatter_edges<<<XB, b256, 0, stream>>>(src, dst, cur, esrc);

  // ---- layer 1
  gemm1_mfma<<<G1, b256, 0, stream>>>(x, btg1, b1s, b1d, hs1h, hd1h);
  node_attn1<<<(N_NODES+3)/4, b256, 0, stream>>>(hs1h, hd1h, row, deg, esrc, a1, h1h);

  // ---- layer 2
  gemm2_mfma<<<G2, b256, 0, stream>>>(h1h, btg2, b2s, b2d, hs2h, hd2h);
  node_attn2<<<(N_NODES+3)/4, b256, 0, stream>>>(hs2h, hd2h, row, deg, esrc, a2, out);
}